// Round 1
// baseline (14009.740 us; speedup 1.0000x reference)
//
#include <hip/hip_runtime.h>
#include <hip/hip_bf16.h>

#define L_ 6
#define D_ 768
#define H_ 12
#define HD_ 64
#define FF_ 3072
#define V_ 32000
#define B_ 4
#define T_ 1024
#define M_ 4096  // B_*T_

typedef __attribute__((ext_vector_type(8))) short short8;   // 8 bf16 = 4 VGPRs (MFMA A/B frag)
typedef __attribute__((ext_vector_type(4))) float f32x4;    // MFMA C/D frag
typedef __hip_bfloat16 bf16;

// ---------------- embedding: h[b,t,:] = tok_emb[x[b,t],:] + pos_emb[t,:] ----------------
__global__ void embed_kernel(const int* __restrict__ x, const float* __restrict__ tok,
                             const float* __restrict__ pos, float* __restrict__ h) {
    int rt = blockIdx.x;            // b*T + t
    int t = rt & (T_ - 1);
    int tokid = x[rt];
    const float* ts = tok + (size_t)tokid * D_;
    const float* ps = pos + (size_t)t * D_;
    float* hr = h + (size_t)rt * D_;
    for (int k = threadIdx.x; k < D_; k += 256)
        hr[k] = ts[k] + ps[k];
}

// ---------------- layernorm (fp32 in, bf16 out), one 256-thread block per row ----------------
__global__ void ln_kernel(const float* __restrict__ x, const float* __restrict__ sc,
                          const float* __restrict__ bi, bf16* __restrict__ out) {
    int row = blockIdx.x, tid = threadIdx.x;
    const float* xr = x + (size_t)row * D_;
    float v0 = xr[tid], v1 = xr[tid + 256], v2 = xr[tid + 512];
    float s = v0 + v1 + v2;
#pragma unroll
    for (int m = 32; m; m >>= 1) s += __shfl_xor(s, m);
    __shared__ float r1[4], r2[4];
    if ((tid & 63) == 0) r1[tid >> 6] = s;
    __syncthreads();
    float mean = (r1[0] + r1[1] + r1[2] + r1[3]) * (1.f / D_);
    float d0 = v0 - mean, d1 = v1 - mean, d2 = v2 - mean;
    float q = d0 * d0 + d1 * d1 + d2 * d2;
#pragma unroll
    for (int m = 32; m; m >>= 1) q += __shfl_xor(q, m);
    if ((tid & 63) == 0) r2[tid >> 6] = q;
    __syncthreads();
    float var = (r2[0] + r2[1] + r2[2] + r2[3]) * (1.f / D_);
    float rs = rsqrtf(var + 1e-5f);
    bf16* orow = out + (size_t)row * D_;
    orow[tid]       = __float2bfloat16(d0 * rs * sc[tid]       + bi[tid]);
    orow[tid + 256] = __float2bfloat16(d1 * rs * sc[tid + 256] + bi[tid + 256]);
    orow[tid + 512] = __float2bfloat16(d2 * rs * sc[tid + 512] + bi[tid + 512]);
}

// ---------------- transpose + fp32->bf16: out[n+off][k] = in[k][n], layer-batched in z ----------------
__global__ void transpose_cvt(const float* __restrict__ in, bf16* __restrict__ out,
                              int K, int N, size_t inLS, size_t outLS,
                              int outStride, int outRowOff) {
    in  += (size_t)blockIdx.z * inLS;
    out += (size_t)blockIdx.z * outLS;
    __shared__ float tile[32][33];
    int n0 = blockIdx.x * 32, k0 = blockIdx.y * 32;
    int tx = threadIdx.x, ty = threadIdx.y;  // 32 x 8
#pragma unroll
    for (int i = 0; i < 4; i++)
        tile[ty + i * 8][tx] = in[(size_t)(k0 + ty + i * 8) * N + n0 + tx];
    __syncthreads();
#pragma unroll
    for (int i = 0; i < 4; i++)
        out[(size_t)(n0 + ty + i * 8 + outRowOff) * outStride + k0 + tx] =
            __float2bfloat16(tile[tx][ty + i * 8]);
}

// ---------------- causal attention, online softmax; one wave per (b,h,query-row); lane = head dim ----------------
__global__ void attn_kernel(const float* __restrict__ qkv, bf16* __restrict__ o) {
    int gw = blockIdx.x * 4 + (threadIdx.x >> 6);
    int lane = threadIdx.x & 63;
    int trow = gw & (T_ - 1);
    int bh = gw >> 10;                      // T_ = 1024
    int b = bh / H_, h = bh % H_;
    const float* base = qkv + (size_t)(b * T_) * (3 * D_);
    float qv = base[(size_t)trow * (3 * D_) + h * HD_ + lane] * 0.125f;  // 1/sqrt(64)
    const float* krow = base + D_ + h * HD_ + lane;
    const float* vrow = base + 2 * D_ + h * HD_ + lane;
    float m = -3.0e38f, l = 0.f, acc = 0.f;
    for (int t = 0; t <= trow; t++) {
        float kv = krow[(size_t)t * (3 * D_)];
        float vv = vrow[(size_t)t * (3 * D_)];
        float p = qv * kv;
#pragma unroll
        for (int mm = 32; mm; mm >>= 1) p += __shfl_xor(p, mm);  // full-wave dot product
        float mn = fmaxf(m, p);
        float alpha = __expf(m - mn);
        float w = __expf(p - mn);
        acc = acc * alpha + w * vv;
        l = l * alpha + w;
        m = mn;
    }
    o[(size_t)(b * T_ + trow) * D_ + h * HD_ + lane] = __float2bfloat16(acc / l);
}

// ---------------- bf16 MFMA GEMM, C = A[M,K] @ B[K,N] with B given transposed (Bt[N][K]) ----------------
// 128x128 tile, BK=32, 4 waves, each wave 64x64 via 4x4 grid of 16x16x32 MFMA.
template <bool OUT_BF16, bool RELU, bool HAS_BIAS, bool HAS_RES>
__global__ __launch_bounds__(256) void gemm_bt(const bf16* __restrict__ A, const bf16* __restrict__ Bt,
                                               const float* __restrict__ bias, const float* __restrict__ res,
                                               void* __restrict__ outp, int M, int N, int K) {
    __shared__ bf16 As[128 * 32];
    __shared__ bf16 Bs[128 * 32];
    int bn0 = blockIdx.x * 128, bm0 = blockIdx.y * 128;
    int tid = threadIdx.x;
    int lane = tid & 63, w = tid >> 6;
    int wm = (w & 1) * 64, wn = (w >> 1) * 64;
    f32x4 acc[4][4];
#pragma unroll
    for (int i = 0; i < 4; i++)
#pragma unroll
        for (int j = 0; j < 4; j++) acc[i][j] = (f32x4){0.f, 0.f, 0.f, 0.f};

    for (int kt = 0; kt < K; kt += 32) {
        __syncthreads();  // previous iteration's frag reads done before overwrite
#pragma unroll
        for (int p = 0; p < 2; p++) {
            int idx = tid + p * 256;
            int r = idx >> 2, c = idx & 3;  // row 0..127, 16B chunk 0..3
            *(uint4*)&As[r * 32 + c * 8] = *(const uint4*)(A + (size_t)(bm0 + r) * K + kt + c * 8);
            *(uint4*)&Bs[r * 32 + c * 8] = *(const uint4*)(Bt + (size_t)(bn0 + r) * K + kt + c * 8);
        }
        __syncthreads();
        short8 af[4], bfr[4];
#pragma unroll
        for (int i = 0; i < 4; i++)
            af[i] = *(const short8*)&As[(wm + i * 16 + (lane & 15)) * 32 + (lane >> 4) * 8];
#pragma unroll
        for (int j = 0; j < 4; j++)
            bfr[j] = *(const short8*)&Bs[(wn + j * 16 + (lane & 15)) * 32 + (lane >> 4) * 8];
#pragma unroll
        for (int i = 0; i < 4; i++)
#pragma unroll
            for (int j = 0; j < 4; j++)
                acc[i][j] = __builtin_amdgcn_mfma_f32_16x16x32_bf16(af[i], bfr[j], acc[i][j], 0, 0, 0);
    }

    // epilogue: D[row][col], col = lane&15, row = (lane>>4)*4 + reg   [m89/m91-verified]
    int r4 = (lane >> 4) * 4, cl = lane & 15;
#pragma unroll
    for (int i = 0; i < 4; i++) {
        int row0 = bm0 + wm + i * 16 + r4;
#pragma unroll
        for (int j = 0; j < 4; j++) {
            int col = bn0 + wn + j * 16 + cl;
            float bv = HAS_BIAS ? bias[col] : 0.f;
#pragma unroll
            for (int r = 0; r < 4; r++) {
                int row = row0 + r;
                float v = acc[i][j][r] + bv;
                if (HAS_RES) v += res[(size_t)row * N + col];
                if (RELU) v = fmaxf(v, 0.f);
                if (OUT_BF16)
                    ((bf16*)outp)[(size_t)row * N + col] = __float2bfloat16(v);
                else
                    ((float*)outp)[(size_t)row * N + col] = v;
            }
        }
    }
}

extern "C" void kernel_launch(void* const* d_in, const int* in_sizes, int n_in,
                              void* d_out, int out_size, void* d_ws, size_t ws_size,
                              hipStream_t stream) {
    const int*   x     = (const int*)d_in[0];
    const float* tok   = (const float*)d_in[1];
    const float* pos   = (const float*)d_in[2];
    const float* wq    = (const float*)d_in[3];
    const float* wk    = (const float*)d_in[4];
    const float* wv    = (const float*)d_in[5];
    const float* wo    = (const float*)d_in[6];
    const float* bo    = (const float*)d_in[7];
    const float* ln1s  = (const float*)d_in[8];
    const float* ln1b  = (const float*)d_in[9];
    const float* ln2s  = (const float*)d_in[10];
    const float* ln2b  = (const float*)d_in[11];
    const float* w1    = (const float*)d_in[12];
    const float* b1    = (const float*)d_in[13];
    const float* w2    = (const float*)d_in[14];
    const float* b2    = (const float*)d_in[15];
    const float* lnfs  = (const float*)d_in[16];
    const float* lnfb  = (const float*)d_in[17];
    const float* whead = (const float*)d_in[18];
    const float* bhead = (const float*)d_in[19];
    float* out = (float*)d_out;

    char* ws = (char*)d_ws;
    size_t off = 0;
    auto alloc = [&](size_t bytes) {
        void* p = ws + off;
        off += (bytes + 255) & ~(size_t)255;
        return p;
    };
    bf16*  Wqkv  = (bf16*)alloc((size_t)L_ * 3 * D_ * D_ * 2);   // [L][2304][768] bf16 (B^T, q|k|v packed)
    bf16*  Wot   = (bf16*)alloc((size_t)L_ * D_ * D_ * 2);       // [L][768][768]
    bf16*  W1t   = (bf16*)alloc((size_t)L_ * FF_ * D_ * 2);      // [L][3072][768]
    bf16*  W2t   = (bf16*)alloc((size_t)L_ * D_ * FF_ * 2);      // [L][768][3072]
    bf16*  Wht   = (bf16*)alloc((size_t)V_ * D_ * 2);            // [32000][768]
    float* h     = (float*)alloc((size_t)M_ * D_ * 4);           // residual stream, fp32
    bf16*  abuf  = (bf16*)alloc((size_t)M_ * D_ * 2);            // LN output
    float* qkv   = (float*)alloc((size_t)M_ * 3 * D_ * 4);       // q|k|v fp32
    bf16*  attno = (bf16*)alloc((size_t)M_ * D_ * 2);            // attention out
    bf16*  ffmid = (bf16*)alloc((size_t)M_ * FF_ * 2);           // relu(f@w1+b1)
    (void)ws_size; (void)in_sizes; (void)n_in; (void)out_size;

    dim3 tb(32, 8);
    // weight convert+transpose (every call; ws is re-poisoned)
    transpose_cvt<<<dim3(D_ / 32, D_ / 32, L_), tb, 0, stream>>>(wq, Wqkv, D_, D_, (size_t)D_ * D_, (size_t)3 * D_ * D_, D_, 0);
    transpose_cvt<<<dim3(D_ / 32, D_ / 32, L_), tb, 0, stream>>>(wk, Wqkv, D_, D_, (size_t)D_ * D_, (size_t)3 * D_ * D_, D_, D_);
    transpose_cvt<<<dim3(D_ / 32, D_ / 32, L_), tb, 0, stream>>>(wv, Wqkv, D_, D_, (size_t)D_ * D_, (size_t)3 * D_ * D_, D_, 2 * D_);
    transpose_cvt<<<dim3(D_ / 32, D_ / 32, L_), tb, 0, stream>>>(wo, Wot, D_, D_, (size_t)D_ * D_, (size_t)D_ * D_, D_, 0);
    transpose_cvt<<<dim3(FF_ / 32, D_ / 32, L_), tb, 0, stream>>>(w1, W1t, D_, FF_, (size_t)D_ * FF_, (size_t)FF_ * D_, D_, 0);
    transpose_cvt<<<dim3(D_ / 32, FF_ / 32, L_), tb, 0, stream>>>(w2, W2t, FF_, D_, (size_t)FF_ * D_, (size_t)D_ * FF_, FF_, 0);
    transpose_cvt<<<dim3(V_ / 32, D_ / 32, 1), tb, 0, stream>>>(whead, Wht, D_, V_, 0, 0, D_, 0);

    embed_kernel<<<M_, 256, 0, stream>>>(x, tok, pos, h);

    for (int l = 0; l < L_; l++) {
        ln_kernel<<<M_, 256, 0, stream>>>(h, ln1s + l * D_, ln1b + l * D_, abuf);
        gemm_bt<false, false, false, false><<<dim3(3 * D_ / 128, M_ / 128), 256, 0, stream>>>(
            abuf, Wqkv + (size_t)l * 3 * D_ * D_, nullptr, nullptr, qkv, M_, 3 * D_, D_);
        attn_kernel<<<(B_ * H_ * T_) / 4, 256, 0, stream>>>(qkv, attno);
        gemm_bt<false, false, true, true><<<dim3(D_ / 128, M_ / 128), 256, 0, stream>>>(
            attno, Wot + (size_t)l * D_ * D_, bo + l * D_, h, h, M_, D_, D_);
        ln_kernel<<<M_, 256, 0, stream>>>(h, ln2s + l * D_, ln2b + l * D_, abuf);
        gemm_bt<true, true, true, false><<<dim3(FF_ / 128, M_ / 128), 256, 0, stream>>>(
            abuf, W1t + (size_t)l * FF_ * D_, b1 + l * FF_, nullptr, ffmid, M_, FF_, D_);
        gemm_bt<false, false, true, true><<<dim3(D_ / 128, M_ / 128), 256, 0, stream>>>(
            ffmid, W2t + (size_t)l * D_ * FF_, b2 + l * D_, h, h, M_, D_, FF_);
    }
    ln_kernel<<<M_, 256, 0, stream>>>(h, lnfs, lnfb, abuf);
    gemm_bt<false, false, true, false><<<dim3(V_ / 128, M_ / 128), 256, 0, stream>>>(
        abuf, Wht, bhead, nullptr, out, M_, V_, D_);
}